// Round 1
// baseline (201.059 us; speedup 1.0000x reference)
//
#include <hip/hip_runtime.h>
#include <math.h>

#define BATCH 4
#define LSEQ 2048
#define BL (BATCH*LSEQ)        // 8192
#define DMODEL 256
#define DINNER 512
#define NSTATE 16
#define DTRANK 16
#define NPROJ 48               // DTRANK + 2*NSTATE
#define HORIZ 96
#define NCH 32                 // scan chunks
#define TCH (LSEQ/NCH)         // 64
#define TB 16                  // tokens per x_dbl block

// ---------------- kernel 1: x_in^T = W1 @ X^T  (fp32 tiled GEMM) ----------------
// xinT[j][m] = sum_k W[j*256+k] * X[m*256+k], j in [0,512), m = b*L+t in [0,8192)
__global__ __launch_bounds__(256) void k_inproj(const float* __restrict__ X,
                                                const float* __restrict__ W,
                                                float* __restrict__ xinT) {
  __shared__ float As[16][68]; // [k][j]
  __shared__ float Bs[16][68]; // [k][m]
  const int mb = blockIdx.x;   // 0..127
  const int jb = blockIdx.y;   // 0..7
  const int tid = threadIdx.x;
  const int tj = tid >> 4;     // 0..15
  const int tm = tid & 15;     // 0..15
  const int j0 = jb * 64, m0 = mb * 64;
  const int lrow = tid >> 2;          // 0..63
  const int lk4  = (tid & 3) << 2;    // 0,4,8,12
  float acc[4][4] = {};
  for (int k0 = 0; k0 < DMODEL; k0 += 16) {
    float4 a = *reinterpret_cast<const float4*>(&W[(size_t)(j0 + lrow) * DMODEL + k0 + lk4]);
    float4 b = *reinterpret_cast<const float4*>(&X[(size_t)(m0 + lrow) * DMODEL + k0 + lk4]);
    As[lk4 + 0][lrow] = a.x; As[lk4 + 1][lrow] = a.y; As[lk4 + 2][lrow] = a.z; As[lk4 + 3][lrow] = a.w;
    Bs[lk4 + 0][lrow] = b.x; Bs[lk4 + 1][lrow] = b.y; Bs[lk4 + 2][lrow] = b.z; Bs[lk4 + 3][lrow] = b.w;
    __syncthreads();
    #pragma unroll
    for (int k = 0; k < 16; ++k) {
      float4 av = *reinterpret_cast<const float4*>(&As[k][tj << 2]);
      float4 bv = *reinterpret_cast<const float4*>(&Bs[k][tm << 2]);
      float aa[4] = {av.x, av.y, av.z, av.w};
      float bb[4] = {bv.x, bv.y, bv.z, bv.w};
      #pragma unroll
      for (int i = 0; i < 4; ++i)
        #pragma unroll
        for (int jj = 0; jj < 4; ++jj) acc[i][jj] = fmaf(aa[i], bb[jj], acc[i][jj]);
    }
    __syncthreads();
  }
  #pragma unroll
  for (int i = 0; i < 4; ++i) {
    float4 v = make_float4(acc[i][0], acc[i][1], acc[i][2], acc[i][3]);
    *reinterpret_cast<float4*>(&xinT[(size_t)(j0 + (tj << 2) + i) * BL + m0 + (tm << 2)]) = v;
  }
}

// ---------------- kernel 1b: z at last timestep ----------------
__global__ __launch_bounds__(256) void k_zlast(const float* __restrict__ X,
                                               const float* __restrict__ W,
                                               float* __restrict__ zbuf) {
  int g = blockIdx.x * 256 + threadIdx.x;   // 0..2047
  int b = g >> 9, j = g & 511;
  const float* xr = &X[((size_t)b * LSEQ + (LSEQ - 1)) * DMODEL];
  const float* wr = &W[(size_t)(DINNER + j) * DMODEL];
  float s = 0.f;
  #pragma unroll 4
  for (int k = 0; k < DMODEL; ++k) s = fmaf(xr[k], wr[k], s);
  zbuf[g] = s;
}

// ---------------- kernel 2: causal depthwise conv + bias + silu -> uT ----------------
__global__ __launch_bounds__(256) void k_conv(const float* __restrict__ xinT,
                                              const float* __restrict__ cw,
                                              const float* __restrict__ cb,
                                              float* __restrict__ uT) {
  size_t idx = (size_t)blockIdx.x * 256 + threadIdx.x; // d*BL + bt
  int bt = (int)(idx & (BL - 1));
  int d  = (int)(idx >> 13);
  int t  = bt & (LSEQ - 1);
  float w0 = cw[d * 4 + 0], w1 = cw[d * 4 + 1], w2 = cw[d * 4 + 2], w3 = cw[d * 4 + 3];
  float acc = cb[d];
  acc = fmaf(w3, xinT[idx], acc);
  if (t >= 1) acc = fmaf(w2, xinT[idx - 1], acc);
  if (t >= 2) acc = fmaf(w1, xinT[idx - 2], acc);
  if (t >= 3) acc = fmaf(w0, xinT[idx - 3], acc);
  uT[idx] = acc / (1.f + expf(-acc));
}

// ---------------- transpose x_proj_w once: xpwT[k][o] ----------------
__global__ __launch_bounds__(256) void k_xpwT(const float* __restrict__ xpw,
                                              float* __restrict__ xpwT) {
  int g = blockIdx.x * 256 + threadIdx.x;  // 24576
  int o = g >> 9, k = g & 511;
  xpwT[(size_t)k * NPROJ + o] = xpw[g];
}

// ---------------- kernel 3a: x_dbl partial GEMV: part[kp][bt][o] ----------------
// lane = output o (48 active of 64); TB tokens per block; u via uniform scalar loads
__global__ __launch_bounds__(64) void k_xdbl(const float* __restrict__ uT,
                                             const float* __restrict__ xpwT,
                                             float* __restrict__ part) {
  const int btc = blockIdx.x;       // 0..511
  const int kp  = blockIdx.y;       // 0..1
  const int o   = threadIdx.x;      // 0..63, active < 48
  const int bt0 = btc * TB;
  float acc[TB];
  #pragma unroll
  for (int j = 0; j < TB; ++j) acc[j] = 0.f;
  const int k0 = kp * 256;
  #pragma unroll 2
  for (int k = k0; k < k0 + 256; ++k) {
    float w = xpwT[(size_t)k * NPROJ + o];   // padded alloc makes o>=48 safe
    #pragma unroll
    for (int j = 0; j < TB; ++j)
      acc[j] = fmaf(w, uT[(size_t)k * BL + bt0 + j], acc[j]);
  }
  if (o < NPROJ) {
    #pragma unroll
    for (int j = 0; j < TB; ++j)
      part[((size_t)kp * BL + bt0 + j) * NPROJ + o] = acc[j];
  }
}

// ---------------- kernel 3b: reduce the 2 K-partials -> dbl[bt][48] ----------------
__global__ __launch_bounds__(256) void k_xdbl_reduce(const float* __restrict__ part,
                                                     float* __restrict__ dbl) {
  int bt = blockIdx.x * 256 + threadIdx.x; // 8192
  #pragma unroll
  for (int o = 0; o < NPROJ; o += 4) {
    float4 a = *reinterpret_cast<const float4*>(&part[(size_t)bt * NPROJ + o]);
    float4 b = *reinterpret_cast<const float4*>(&part[((size_t)BL + bt) * NPROJ + o]);
    float4 v = make_float4(a.x + b.x, a.y + b.y, a.z + b.z, a.w + b.w);
    *reinterpret_cast<float4*>(&dbl[(size_t)bt * NPROJ + o]) = v;
  }
}

// ---------------- kernel 3c: delta = softplus(dt_raw @ dtw^T + dtb) -> deltaT ----------------
__global__ __launch_bounds__(256) void k_delta(const float* __restrict__ dbl,
                                               const float* __restrict__ dtw,
                                               const float* __restrict__ dtb,
                                               float* __restrict__ deltaT) {
  __shared__ float sB[64][17];
  __shared__ float sW[64][17];
  const int bt0 = blockIdx.x * 64;
  const int d0  = blockIdx.y * 64;
  const int tid = threadIdx.x;
  {
    int row = tid >> 2, c4 = (tid & 3) << 2;
    float4 vb = *reinterpret_cast<const float4*>(&dbl[(size_t)(bt0 + row) * NPROJ + c4]);
    sB[row][c4 + 0] = vb.x; sB[row][c4 + 1] = vb.y; sB[row][c4 + 2] = vb.z; sB[row][c4 + 3] = vb.w;
    float4 vw = *reinterpret_cast<const float4*>(&dtw[(size_t)(d0 + row) * DTRANK + c4]);
    sW[row][c4 + 0] = vw.x; sW[row][c4 + 1] = vw.y; sW[row][c4 + 2] = vw.z; sW[row][c4 + 3] = vw.w;
  }
  __syncthreads();
  const int btl = tid & 63;
  const int dl0 = tid >> 6;            // 0..3
  #pragma unroll
  for (int q = 0; q < 16; ++q) {
    int dl = dl0 + (q << 2);
    int d = d0 + dl;
    float acc = dtb[d];
    #pragma unroll
    for (int r = 0; r < DTRANK; ++r) acc = fmaf(sB[btl][r], sW[dl][r], acc);
    float sp = (acc > 20.f) ? acc : log1pf(expf(acc));
    deltaT[(size_t)d * BL + bt0 + btl] = sp;
  }
}

// ---------------- kernel 4: chunked scan: per-chunk (prod a, h from 0) ----------------
__global__ __launch_bounds__(256) void k_scan(const float* __restrict__ deltaT,
                                              const float* __restrict__ uT,
                                              const float* __restrict__ dbl,
                                              const float* __restrict__ Alog,
                                              float* __restrict__ aprod,
                                              float* __restrict__ hacc) {
  const int dblk = blockIdx.x;  // 0..31
  const int c    = blockIdx.y;  // 0..31
  const int b    = blockIdx.z;  // 0..3
  const int tid  = threadIdx.x;
  const int dl = tid >> 4;      // 0..15
  const int n  = tid & 15;
  const int d  = dblk * 16 + dl;
  const float A = -expf(Alog[d * NSTATE + n]);
  float ap = 1.f, h = 0.f;
  const int bt0 = b * LSEQ + c * TCH;
  for (int tt = 0; tt < TCH; ++tt) {
    int bt = bt0 + tt;
    float dlt = deltaT[(size_t)d * BL + bt];
    float uv  = uT[(size_t)d * BL + bt];
    float Bv  = dbl[(size_t)bt * NPROJ + DTRANK + n];
    float dA  = __expf(dlt * A);
    h = fmaf(dA, h, dlt * Bv * uv);
    ap *= dA;
  }
  size_t off = (((size_t)b * NCH + c) * DINNER + d) * NSTATE + n;
  aprod[off] = ap;
  hacc[off]  = h;
}

// ---------------- kernel 5a: combine chunks, y at last step ----------------
__global__ __launch_bounds__(256) void k_combine(const float* __restrict__ aprod,
                                                 const float* __restrict__ hacc,
                                                 const float* __restrict__ dbl,
                                                 const float* __restrict__ uT,
                                                 const float* __restrict__ Dp,
                                                 const float* __restrict__ zbuf,
                                                 float* __restrict__ ybuf) {
  const int dblk = blockIdx.x & 31, b = blockIdx.x >> 5;
  const int tid = threadIdx.x;
  const int dl = tid >> 4, n = tid & 15;
  const int d = dblk * 16 + dl;
  float h = 0.f;
  for (int c = 0; c < NCH; ++c) {
    size_t off = (((size_t)b * NCH + c) * DINNER + d) * NSTATE + n;
    h = fmaf(aprod[off], h, hacc[off]);
  }
  const int btL = b * LSEQ + LSEQ - 1;
  float Cv = dbl[(size_t)btL * NPROJ + DTRANK + NSTATE + n];
  float v = h * Cv;
  v += __shfl_xor(v, 1);
  v += __shfl_xor(v, 2);
  v += __shfl_xor(v, 4);
  v += __shfl_xor(v, 8);
  if (n == 0) {
    float y = v + uT[(size_t)d * BL + btL] * Dp[d];
    float z = zbuf[b * DINNER + d];
    y *= z / (1.f + expf(-z));
    ybuf[b * DINNER + d] = y;
  }
}

// ---------------- kernel 5b: out_proj + head for last step ----------------
__global__ __launch_bounds__(256) void k_head(const float* __restrict__ ybuf,
                                              const float* __restrict__ opw,
                                              const float* __restrict__ hw,
                                              const float* __restrict__ hb,
                                              float* __restrict__ out) {
  __shared__ float ys[DINNER];
  __shared__ float ov[DMODEL];
  const int b = blockIdx.x, tid = threadIdx.x;
  ys[tid]       = ybuf[b * DINNER + tid];
  ys[tid + 256] = ybuf[b * DINNER + tid + 256];
  __syncthreads();
  float s = 0.f;
  const float* wr = &opw[(size_t)tid * DINNER];
  #pragma unroll 4
  for (int k = 0; k < DINNER; ++k) s = fmaf(ys[k], wr[k], s);
  ov[tid] = s;
  __syncthreads();
  if (tid < HORIZ) {
    float acc = hb[tid];
    const float* hr = &hw[(size_t)tid * DMODEL];
    #pragma unroll 4
    for (int k = 0; k < DMODEL; ++k) acc = fmaf(ov[k], hr[k], acc);
    out[b * HORIZ + tid] = acc;
  }
}

extern "C" void kernel_launch(void* const* d_in, const int* in_sizes, int n_in,
                              void* d_out, int out_size, void* d_ws, size_t ws_size,
                              hipStream_t stream) {
  const float* x    = (const float*)d_in[0];
  const float* ipw  = (const float*)d_in[1];
  const float* cw   = (const float*)d_in[2];
  const float* cb   = (const float*)d_in[3];
  const float* xpw  = (const float*)d_in[4];
  const float* dtw  = (const float*)d_in[5];
  const float* dtb  = (const float*)d_in[6];
  const float* Alog = (const float*)d_in[7];
  const float* Dp   = (const float*)d_in[8];
  const float* opw  = (const float*)d_in[9];
  const float* hw   = (const float*)d_in[10];
  const float* hb   = (const float*)d_in[11];
  float* out = (float*)d_out;
  float* ws  = (float*)d_ws;

  // workspace layout (floats)
  float* xinT   = ws;                         // 4,194,304 (reused as deltaT)
  float* uT     = ws + 4194304;               // 4,194,304
  float* dbl    = ws + 8388608;               //   393,216
  float* part   = ws + 8781824;               //   786,432 (dead after reduce)
  float* aprod  = ws + 8781824;               // 1,048,576 (overlaps part - OK)
  float* hacc   = ws + 9830400;               // 1,048,576
  float* zbuf   = ws + 10878976;              //     2,048
  float* ybuf   = ws + 10881024;              //     2,048
  float* xpwT   = ws + 10883072;              //    24,640 (padded)
  float* deltaT = xinT;

  k_xpwT<<<96, 256, 0, stream>>>(xpw, xpwT);
  k_inproj<<<dim3(128, 8), 256, 0, stream>>>(x, ipw, xinT);
  k_zlast<<<8, 256, 0, stream>>>(x, ipw, zbuf);
  k_conv<<<16384, 256, 0, stream>>>(xinT, cw, cb, uT);
  k_xdbl<<<dim3(512, 2), 64, 0, stream>>>(uT, xpwT, part);
  k_xdbl_reduce<<<32, 256, 0, stream>>>(part, dbl);
  k_delta<<<dim3(128, 8), 256, 0, stream>>>(dbl, dtw, dtb, deltaT);
  k_scan<<<dim3(32, NCH, BATCH), 256, 0, stream>>>(deltaT, uT, dbl, Alog, aprod, hacc);
  k_combine<<<128, 256, 0, stream>>>(aprod, hacc, dbl, uT, Dp, zbuf, ybuf);
  k_head<<<4, 256, 0, stream>>>(ybuf, opw, hw, hb, out);
}

// Round 2
// 155.923 us; speedup vs baseline: 1.2895x; 1.2895x over previous
//
#include <hip/hip_runtime.h>
#include <math.h>

#define BATCH 4
#define LSEQ 2048
#define BL (BATCH*LSEQ)        // 8192
#define DMODEL 256
#define DINNER 512
#define NSTATE 16
#define DTRANK 16
#define NPROJ 48               // DTRANK + 2*NSTATE
#define HORIZ 96
#define NCH 32                 // scan chunks
#define TCH (LSEQ/NCH)         // 64
#define MT 64                  // tokens per x_dbl block
#define KPART 4                // K splits for x_dbl
#define KC (DINNER/KPART)      // 128 k per block
#define KT 32                  // k per LDS stage

// ---------------- kernel 1: x_in^T = W1 @ X^T  (fp32 tiled GEMM) ----------------
// xinT[j][m] = sum_k W[j*256+k] * X[m*256+k], j in [0,512), m = b*L+t in [0,8192)
__global__ __launch_bounds__(256) void k_inproj(const float* __restrict__ X,
                                                const float* __restrict__ W,
                                                float* __restrict__ xinT) {
  __shared__ float As[16][68]; // [k][j]
  __shared__ float Bs[16][68]; // [k][m]
  const int mb = blockIdx.x;   // 0..127
  const int jb = blockIdx.y;   // 0..7
  const int tid = threadIdx.x;
  const int tj = tid >> 4;     // 0..15
  const int tm = tid & 15;     // 0..15
  const int j0 = jb * 64, m0 = mb * 64;
  const int lrow = tid >> 2;          // 0..63
  const int lk4  = (tid & 3) << 2;    // 0,4,8,12
  float acc[4][4] = {};
  for (int k0 = 0; k0 < DMODEL; k0 += 16) {
    float4 a = *reinterpret_cast<const float4*>(&W[(size_t)(j0 + lrow) * DMODEL + k0 + lk4]);
    float4 b = *reinterpret_cast<const float4*>(&X[(size_t)(m0 + lrow) * DMODEL + k0 + lk4]);
    As[lk4 + 0][lrow] = a.x; As[lk4 + 1][lrow] = a.y; As[lk4 + 2][lrow] = a.z; As[lk4 + 3][lrow] = a.w;
    Bs[lk4 + 0][lrow] = b.x; Bs[lk4 + 1][lrow] = b.y; Bs[lk4 + 2][lrow] = b.z; Bs[lk4 + 3][lrow] = b.w;
    __syncthreads();
    #pragma unroll
    for (int k = 0; k < 16; ++k) {
      float4 av = *reinterpret_cast<const float4*>(&As[k][tj << 2]);
      float4 bv = *reinterpret_cast<const float4*>(&Bs[k][tm << 2]);
      float aa[4] = {av.x, av.y, av.z, av.w};
      float bb[4] = {bv.x, bv.y, bv.z, bv.w};
      #pragma unroll
      for (int i = 0; i < 4; ++i)
        #pragma unroll
        for (int jj = 0; jj < 4; ++jj) acc[i][jj] = fmaf(aa[i], bb[jj], acc[i][jj]);
    }
    __syncthreads();
  }
  #pragma unroll
  for (int i = 0; i < 4; ++i) {
    float4 v = make_float4(acc[i][0], acc[i][1], acc[i][2], acc[i][3]);
    *reinterpret_cast<float4*>(&xinT[(size_t)(j0 + (tj << 2) + i) * BL + m0 + (tm << 2)]) = v;
  }
}

// ---------------- kernel 1b: z at last timestep (one wave per (b,j) dot) ----------------
__global__ __launch_bounds__(256) void k_zlast(const float* __restrict__ X,
                                               const float* __restrict__ W,
                                               float* __restrict__ zbuf) {
  const int wid = blockIdx.x * 4 + (threadIdx.x >> 6);  // 0..2047
  const int lane = threadIdx.x & 63;
  const int b = wid >> 9, j = wid & 511;
  const float* xr = &X[((size_t)b * LSEQ + (LSEQ - 1)) * DMODEL];
  const float* wr = &W[(size_t)(DINNER + j) * DMODEL];
  float4 xv = *reinterpret_cast<const float4*>(&xr[lane << 2]);
  float4 wv = *reinterpret_cast<const float4*>(&wr[lane << 2]);
  float s = xv.x * wv.x + xv.y * wv.y + xv.z * wv.z + xv.w * wv.w;
  #pragma unroll
  for (int off = 1; off < 64; off <<= 1) s += __shfl_xor(s, off);
  if (lane == 0) zbuf[wid] = s;
}

// ---------------- kernel 2: causal depthwise conv + bias + silu -> uT ----------------
__global__ __launch_bounds__(256) void k_conv(const float* __restrict__ xinT,
                                              const float* __restrict__ cw,
                                              const float* __restrict__ cb,
                                              float* __restrict__ uT) {
  size_t idx = (size_t)blockIdx.x * 256 + threadIdx.x; // d*BL + bt
  int bt = (int)(idx & (BL - 1));
  int d  = (int)(idx >> 13);
  int t  = bt & (LSEQ - 1);
  float w0 = cw[d * 4 + 0], w1 = cw[d * 4 + 1], w2 = cw[d * 4 + 2], w3 = cw[d * 4 + 3];
  float acc = cb[d];
  acc = fmaf(w3, xinT[idx], acc);
  if (t >= 1) acc = fmaf(w2, xinT[idx - 1], acc);
  if (t >= 2) acc = fmaf(w1, xinT[idx - 2], acc);
  if (t >= 3) acc = fmaf(w0, xinT[idx - 3], acc);
  uT[idx] = acc / (1.f + expf(-acc));
}

// ---------------- transpose x_proj_w once: xpwT[k][o] ----------------
__global__ __launch_bounds__(256) void k_xpwT(const float* __restrict__ xpw,
                                              float* __restrict__ xpwT) {
  int g = blockIdx.x * 256 + threadIdx.x;  // 24576
  int o = g >> 9, k = g & 511;
  xpwT[(size_t)k * NPROJ + o] = xpw[g];
}

// ---------------- kernel 3a: x_dbl tiled GEMM partials: part[kp][bt][o] ----------------
// dbl[bt][o] = sum_k uT[k][bt] * xpwT[k][o]; block = 64 tokens x 48 outs x 128 k
__global__ __launch_bounds__(256) void k_xdbl(const float* __restrict__ uT,
                                              const float* __restrict__ xpwT,
                                              float* __restrict__ part) {
  __shared__ float su[KT][MT];        // 8 KB
  __shared__ float sw[KC * NPROJ];    // 24 KB (weight chunk, linear copy)
  const int btc = blockIdx.x;         // 0..127
  const int kp  = blockIdx.y;         // 0..3
  const int bt0 = btc * MT;
  const int kbase = kp * KC;
  const int tid = threadIdx.x;
  const int t0 = (tid & 15) << 2;     // token offset 0..60
  const int o0 = (tid >> 4) * 3;      // out offset 0..45
  float acc[4][3] = {};
  // stage full weight chunk (contiguous rows of xpwT)
  {
    const float4* src = reinterpret_cast<const float4*>(&xpwT[(size_t)kbase * NPROJ]);
    float4* dst = reinterpret_cast<float4*>(sw);
    #pragma unroll
    for (int i = tid; i < (KC * NPROJ) / 4; i += 256) dst[i] = src[i];
  }
  for (int ks = 0; ks < KC; ks += KT) {
    // stage u tile: KT x MT = 2048 floats = 512 float4, 2 per thread
    #pragma unroll
    for (int r = 0; r < 2; ++r) {
      int i = tid + r * 256;
      int kk = i >> 4;
      int tt = (i & 15) << 2;
      *reinterpret_cast<float4*>(&su[kk][tt]) =
        *reinterpret_cast<const float4*>(&uT[(size_t)(kbase + ks + kk) * BL + bt0 + tt]);
    }
    __syncthreads();
    #pragma unroll 4
    for (int kk = 0; kk < KT; ++kk) {
      float4 uv = *reinterpret_cast<const float4*>(&su[kk][t0]);
      float uu[4] = {uv.x, uv.y, uv.z, uv.w};
      const float* wr = &sw[(ks + kk) * NPROJ + o0];
      float ww[3] = {wr[0], wr[1], wr[2]};
      #pragma unroll
      for (int i = 0; i < 4; ++i)
        #pragma unroll
        for (int j = 0; j < 3; ++j) acc[i][j] = fmaf(uu[i], ww[j], acc[i][j]);
    }
    __syncthreads();
  }
  #pragma unroll
  for (int i = 0; i < 4; ++i)
    #pragma unroll
    for (int j = 0; j < 3; ++j)
      part[((size_t)kp * BL + bt0 + t0 + i) * NPROJ + o0 + j] = acc[i][j];
}

// ---------------- kernel 3b: reduce the 4 K-partials -> dbl[bt][48] ----------------
__global__ __launch_bounds__(256) void k_xdbl_reduce(const float* __restrict__ part,
                                                     float* __restrict__ dbl) {
  const int g = blockIdx.x * 256 + threadIdx.x;  // 0..98303 (float4 index)
  const int stride = BL * NPROJ / 4;             // 98304
  const float4* p = reinterpret_cast<const float4*>(part);
  float4 a = p[g], b = p[g + stride], c = p[g + 2 * stride], d = p[g + 3 * stride];
  float4 v = make_float4(a.x + b.x + c.x + d.x, a.y + b.y + c.y + d.y,
                         a.z + b.z + c.z + d.z, a.w + b.w + c.w + d.w);
  reinterpret_cast<float4*>(dbl)[g] = v;
}

// ---------------- kernel 3c: delta = softplus(dt_raw @ dtw^T + dtb) -> deltaT ----------------
__global__ __launch_bounds__(256) void k_delta(const float* __restrict__ dbl,
                                               const float* __restrict__ dtw,
                                               const float* __restrict__ dtb,
                                               float* __restrict__ deltaT) {
  __shared__ float sB[64][17];
  __shared__ float sW[64][17];
  const int bt0 = blockIdx.x * 64;
  const int d0  = blockIdx.y * 64;
  const int tid = threadIdx.x;
  {
    int row = tid >> 2, c4 = (tid & 3) << 2;
    float4 vb = *reinterpret_cast<const float4*>(&dbl[(size_t)(bt0 + row) * NPROJ + c4]);
    sB[row][c4 + 0] = vb.x; sB[row][c4 + 1] = vb.y; sB[row][c4 + 2] = vb.z; sB[row][c4 + 3] = vb.w;
    float4 vw = *reinterpret_cast<const float4*>(&dtw[(size_t)(d0 + row) * DTRANK + c4]);
    sW[row][c4 + 0] = vw.x; sW[row][c4 + 1] = vw.y; sW[row][c4 + 2] = vw.z; sW[row][c4 + 3] = vw.w;
  }
  __syncthreads();
  const int btl = tid & 63;
  const int dl0 = tid >> 6;            // 0..3
  #pragma unroll
  for (int q = 0; q < 16; ++q) {
    int dl = dl0 + (q << 2);
    int d = d0 + dl;
    float acc = dtb[d];
    #pragma unroll
    for (int r = 0; r < DTRANK; ++r) acc = fmaf(sB[btl][r], sW[dl][r], acc);
    float sp = (acc > 20.f) ? acc : log1pf(expf(acc));
    deltaT[(size_t)d * BL + bt0 + btl] = sp;
  }
}

// ---------------- kernel 4: chunked scan: per-chunk (prod a, h from 0) ----------------
__global__ __launch_bounds__(256) void k_scan(const float* __restrict__ deltaT,
                                              const float* __restrict__ uT,
                                              const float* __restrict__ dbl,
                                              const float* __restrict__ Alog,
                                              float* __restrict__ aprod,
                                              float* __restrict__ hacc) {
  const int dblk = blockIdx.x;  // 0..31
  const int c    = blockIdx.y;  // 0..31
  const int b    = blockIdx.z;  // 0..3
  const int tid  = threadIdx.x;
  const int dl = tid >> 4;      // 0..15
  const int n  = tid & 15;
  const int d  = dblk * 16 + dl;
  const float A = -expf(Alog[d * NSTATE + n]);
  float ap = 1.f, h = 0.f;
  const int bt0 = b * LSEQ + c * TCH;
  for (int tt = 0; tt < TCH; ++tt) {
    int bt = bt0 + tt;
    float dlt = deltaT[(size_t)d * BL + bt];
    float uv  = uT[(size_t)d * BL + bt];
    float Bv  = dbl[(size_t)bt * NPROJ + DTRANK + n];
    float dA  = __expf(dlt * A);
    h = fmaf(dA, h, dlt * Bv * uv);
    ap *= dA;
  }
  size_t off = (((size_t)b * NCH + c) * DINNER + d) * NSTATE + n;
  aprod[off] = ap;
  hacc[off]  = h;
}

// ---------------- kernel 5a: combine chunks, y at last step ----------------
__global__ __launch_bounds__(256) void k_combine(const float* __restrict__ aprod,
                                                 const float* __restrict__ hacc,
                                                 const float* __restrict__ dbl,
                                                 const float* __restrict__ uT,
                                                 const float* __restrict__ Dp,
                                                 const float* __restrict__ zbuf,
                                                 float* __restrict__ ybuf) {
  const int dblk = blockIdx.x & 31, b = blockIdx.x >> 5;
  const int tid = threadIdx.x;
  const int dl = tid >> 4, n = tid & 15;
  const int d = dblk * 16 + dl;
  float h = 0.f;
  for (int c = 0; c < NCH; ++c) {
    size_t off = (((size_t)b * NCH + c) * DINNER + d) * NSTATE + n;
    h = fmaf(aprod[off], h, hacc[off]);
  }
  const int btL = b * LSEQ + LSEQ - 1;
  float Cv = dbl[(size_t)btL * NPROJ + DTRANK + NSTATE + n];
  float v = h * Cv;
  v += __shfl_xor(v, 1);
  v += __shfl_xor(v, 2);
  v += __shfl_xor(v, 4);
  v += __shfl_xor(v, 8);
  if (n == 0) {
    float y = v + uT[(size_t)d * BL + btL] * Dp[d];
    float z = zbuf[b * DINNER + d];
    y *= z / (1.f + expf(-z));
    ybuf[b * DINNER + d] = y;
  }
}

// ---------------- kernel 5b: out_proj + head for last step ----------------
__global__ __launch_bounds__(256) void k_head(const float* __restrict__ ybuf,
                                              const float* __restrict__ opw,
                                              const float* __restrict__ hw,
                                              const float* __restrict__ hb,
                                              float* __restrict__ out) {
  __shared__ float ys[DINNER];
  __shared__ float ov[DMODEL];
  const int b = blockIdx.x, tid = threadIdx.x;
  ys[tid]       = ybuf[b * DINNER + tid];
  ys[tid + 256] = ybuf[b * DINNER + tid + 256];
  __syncthreads();
  float s = 0.f;
  const float* wr = &opw[(size_t)tid * DINNER];
  #pragma unroll 4
  for (int k = 0; k < DINNER; ++k) s = fmaf(ys[k], wr[k], s);
  ov[tid] = s;
  __syncthreads();
  if (tid < HORIZ) {
    float acc = hb[tid];
    const float* hr = &hw[(size_t)tid * DMODEL];
    #pragma unroll 4
    for (int k = 0; k < DMODEL; ++k) acc = fmaf(ov[k], hr[k], acc);
    out[b * HORIZ + tid] = acc;
  }
}

extern "C" void kernel_launch(void* const* d_in, const int* in_sizes, int n_in,
                              void* d_out, int out_size, void* d_ws, size_t ws_size,
                              hipStream_t stream) {
  const float* x    = (const float*)d_in[0];
  const float* ipw  = (const float*)d_in[1];
  const float* cw   = (const float*)d_in[2];
  const float* cb   = (const float*)d_in[3];
  const float* xpw  = (const float*)d_in[4];
  const float* dtw  = (const float*)d_in[5];
  const float* dtb  = (const float*)d_in[6];
  const float* Alog = (const float*)d_in[7];
  const float* Dp   = (const float*)d_in[8];
  const float* opw  = (const float*)d_in[9];
  const float* hw   = (const float*)d_in[10];
  const float* hb   = (const float*)d_in[11];
  float* out = (float*)d_out;
  float* ws  = (float*)d_ws;

  // workspace layout (floats)
  float* xinT   = ws;                         // 4,194,304 (reused as deltaT)
  float* uT     = ws + 4194304;               // 4,194,304
  float* dbl    = ws + 8388608;               //   393,216
  float* part   = ws + 8781824;               // 1,572,864 (dead after reduce)
  float* aprod  = ws + 8781824;               // 1,048,576 (overlaps dead part)
  float* hacc   = ws + 9830400;               // 1,048,576 (overlaps dead part tail)
  float* zbuf   = ws + 10878976;              //     2,048
  float* ybuf   = ws + 10881024;              //     2,048
  float* xpwT   = ws + 10883072;              //    24,576
  float* deltaT = xinT;

  k_xpwT<<<96, 256, 0, stream>>>(xpw, xpwT);
  k_inproj<<<dim3(128, 8), 256, 0, stream>>>(x, ipw, xinT);
  k_zlast<<<512, 256, 0, stream>>>(x, ipw, zbuf);
  k_conv<<<16384, 256, 0, stream>>>(xinT, cw, cb, uT);
  k_xdbl<<<dim3(BL / MT, KPART), 256, 0, stream>>>(uT, xpwT, part);
  k_xdbl_reduce<<<384, 256, 0, stream>>>(part, dbl);
  k_delta<<<dim3(128, 8), 256, 0, stream>>>(dbl, dtw, dtb, deltaT);
  k_scan<<<dim3(32, NCH, BATCH), 256, 0, stream>>>(deltaT, uT, dbl, Alog, aprod, hacc);
  k_combine<<<128, 256, 0, stream>>>(aprod, hacc, dbl, uT, Dp, zbuf, ybuf);
  k_head<<<4, 256, 0, stream>>>(ybuf, opw, hw, hb, out);
}